// Round 14
// baseline (56.113 us; speedup 1.0000x reference)
//
#include <hip/hip_runtime.h>

#define E_TOTAL 262144
#define TPB 512
#define NBLK 512
#define CHUNK 512
#define MAXT 48              // max 16-pair tiles per chunk (hard bound 47)

typedef __attribute__((ext_vector_type(8))) short short8;
typedef __attribute__((ext_vector_type(4))) float f32x4;

__device__ __forceinline__ float silu_f(float x) { return x / (1.0f + __expf(-x)); }

// RNE float -> bf16 bits
__device__ __forceinline__ short f2bf(float f) {
    unsigned int u = __float_as_uint(f);
    u += 0x7fffu + ((u >> 16) & 1u);
    return (short)(u >> 16);
}
__device__ __forceinline__ float bf2f(short s) {
    return __uint_as_float(((unsigned int)(unsigned short)s) << 16);
}

// ---- PHASE 0 ----
// Ballot-sort chunk by type, stage W0/fn bf16 in LDS, MFMA1 x2 per tile,
// BN1 stats -> p1. Publishes for phase 1: bf16 fn (by pair index), slot->pair
// table gsidx, tile-type table gtt.
__global__ __launch_bounds__(TPB, 4)
void nep_p0(const int* __restrict__ ij, const float* __restrict__ fn,
            const float* __restrict__ W0,
            float* __restrict__ p1, short* __restrict__ gfnb,
            short* __restrict__ gsidx, char* __restrict__ gtt)
{
    __shared__ __align__(16) short sW0[16 * 512];   // 16KB
    __shared__ __align__(16) short sfn[CHUNK * 16]; // 16KB
    __shared__ int whist[8][16];
    __shared__ int woff[8][16];
    __shared__ int soff[16];
    __shared__ int tstart[17];
    __shared__ short slotp[MAXT * 16];
    __shared__ char ttype[MAXT];
    __shared__ float rS[8][32], rQ[8][32];

    const int tid  = threadIdx.x;
    const int bid  = blockIdx.x;
    const int l    = tid & 63;
    const int wave = tid >> 6;
    const int p    = l & 15;
    const int hi   = l >> 4;
    const int base = bid * CHUNK;

    const int t0 = ij[base + tid];
    const float4* f4g = (const float4*)(fn + (size_t)(base + tid) * 16);
    float4 u0 = f4g[0], u1 = f4g[1], u2 = f4g[2], u3 = f4g[3];

    // ballot multi-split (stable: wave-major, lane-major)
    unsigned long long bl0 = __ballot(t0 & 1);
    unsigned long long bl1 = __ballot(t0 & 2);
    unsigned long long bl2 = __ballot(t0 & 4);
    unsigned long long bl3 = __ballot(t0 & 8);
    unsigned long long mself = ((t0 & 1) ? bl0 : ~bl0) & ((t0 & 2) ? bl1 : ~bl1)
                             & ((t0 & 4) ? bl2 : ~bl2) & ((t0 & 8) ? bl3 : ~bl3);
    const int rank_w = __popcll(mself & ((1ull << l) - 1ull));
    if (l < 16) {
        const int t = l;
        unsigned long long mt = ((t & 1) ? bl0 : ~bl0) & ((t & 2) ? bl1 : ~bl1)
                              & ((t & 4) ? bl2 : ~bl2) & ((t & 8) ? bl3 : ~bl3);
        whist[wave][t] = __popcll(mt);
    }
    // init LDS + global tables (ordered before scatter by the syncs below)
    if (tid < MAXT * 16 / 2) ((int*)slotp)[tid] = -1;
    if (tid < MAXT) gtt[bid * MAXT + tid] = -1;
    #pragma unroll
    for (int i = tid; i < MAXT * 16; i += TPB) gsidx[bid * MAXT * 16 + i] = -1;

    // stage W0 (fp32 -> bf16)
    {
        const float4* W04 = (const float4*)W0;
        #pragma unroll
        for (int i = 0; i < 4; i++) {
            float4 v = W04[tid + i * TPB];
            short4 s;
            s.x = f2bf(v.x); s.y = f2bf(v.y); s.z = f2bf(v.z); s.w = f2bf(v.w);
            *(short4*)(sW0 + (tid + i * TPB) * 4) = s;
        }
    }
    // fn fp32 -> bf16: LDS + publish to global (coalesced by pair index)
    {
        short8 w0, w1;
        w0[0]=f2bf(u0.x); w0[1]=f2bf(u0.y); w0[2]=f2bf(u0.z); w0[3]=f2bf(u0.w);
        w0[4]=f2bf(u1.x); w0[5]=f2bf(u1.y); w0[6]=f2bf(u1.z); w0[7]=f2bf(u1.w);
        w1[0]=f2bf(u2.x); w1[1]=f2bf(u2.y); w1[2]=f2bf(u2.z); w1[3]=f2bf(u2.w);
        w1[4]=f2bf(u3.x); w1[5]=f2bf(u3.y); w1[6]=f2bf(u3.z); w1[7]=f2bf(u3.w);
        *(short8*)(sfn + tid * 16)     = w0;
        *(short8*)(sfn + tid * 16 + 8) = w1;
        *(short8*)(gfnb + (size_t)(base + tid) * 16)     = w0;
        *(short8*)(gfnb + (size_t)(base + tid) * 16 + 8) = w1;
    }
    __syncthreads();

    if (tid < 16) {
        int acc = 0;
        #pragma unroll
        for (int w = 0; w < 8; w++) { woff[w][tid] = acc; acc += whist[w][tid]; }
        soff[tid] = acc;
    }
    __syncthreads();
    if (tid == 0) {
        int acc = 0;
        #pragma unroll
        for (int t = 0; t < 16; t++) { tstart[t] = acc; acc += (soff[t] + 15) >> 4; }
        tstart[16] = acc;
    }
    __syncthreads();
    {
        const int rank = woff[wave][t0] + rank_w;
        const int ti = tstart[t0] + (rank >> 4);
        slotp[ti * 16 + (rank & 15)] = (short)tid;
        ttype[ti] = (char)t0;                                  // same-value race benign
        gsidx[bid * MAXT * 16 + ti * 16 + (rank & 15)] = (short)tid;
        gtt[bid * MAXT + ti] = (char)t0;                       // same-value race benign
    }
    __syncthreads();
    const int ntiles = tstart[16];

    float s1[8], s2[8];
    #pragma unroll
    for (int c = 0; c < 8; c++) { s1[c] = 0.f; s2[c] = 0.f; }

    #pragma unroll 1
    for (int it = 0; it < 6; it++) {
        const int ti = wave + it * 8;
        if (ti >= ntiles) break;
        const int t  = (int)ttype[ti];
        const int sp = (int)slotp[ti * 16 + p];

        short8 bF = {0,0,0,0,0,0,0,0};
        if (hi < 2 && sp >= 0)
            bF = *(const short8*)(sfn + sp * 16 + hi * 8);
        short8 a0 = {0,0,0,0,0,0,0,0};
        short8 a1 = {0,0,0,0,0,0,0,0};
        if (hi < 2) {
            a0 = *(const short8*)(sW0 + t * 512 + p * 16 + hi * 8);
            a1 = *(const short8*)(sW0 + t * 512 + 256 + p * 16 + hi * 8);
        }
        f32x4 z = {0.f, 0.f, 0.f, 0.f};
        f32x4 c0 = __builtin_amdgcn_mfma_f32_16x16x32_bf16(a0, bF, z, 0, 0, 0);
        f32x4 c1 = __builtin_amdgcn_mfma_f32_16x16x32_bf16(a1, bF, z, 0, 0, 0);
        #pragma unroll
        for (int r = 0; r < 4; r++) {
            s1[r]     += c0[r]; s2[r]     += c0[r] * c0[r];
            s1[4 + r] += c1[r]; s2[4 + r] += c1[r] * c1[r];
        }
    }

    #pragma unroll
    for (int c = 0; c < 8; c++) {
        float v1 = s1[c], v2 = s2[c];
        v1 += __shfl_xor(v1, 1, 64); v2 += __shfl_xor(v2, 1, 64);
        v1 += __shfl_xor(v1, 2, 64); v2 += __shfl_xor(v2, 2, 64);
        v1 += __shfl_xor(v1, 4, 64); v2 += __shfl_xor(v2, 4, 64);
        v1 += __shfl_xor(v1, 8, 64); v2 += __shfl_xor(v2, 8, 64);
        s1[c] = v1; s2[c] = v2;
    }
    if (p == 0) {
        #pragma unroll
        for (int r = 0; r < 4; r++) {
            rS[wave][hi * 4 + r]      = s1[r];     rQ[wave][hi * 4 + r]      = s2[r];
            rS[wave][16 + hi * 4 + r] = s1[4 + r]; rQ[wave][16 + hi * 4 + r] = s2[4 + r];
        }
    }
    __syncthreads();
    if (tid < 32) {
        float a = 0.f, b = 0.f;
        #pragma unroll
        for (int w = 0; w < 8; w++) { a += rS[w][tid]; b += rQ[w][tid]; }
        p1[bid * 64 + tid]      = a;
        p1[bid * 64 + 32 + tid] = b;
    }
}

// ---- PHASE 1 ----
// Redundant deterministic fold of p1 -> BN1 affine (per block, L2-hot), then
// tile MFMAs using phase-0's tables + bf16 fn (no sort, no fp32 fn read).
// Writes pre-BN2 o2 (bf16) + BN2 stats -> p2.
__global__ __launch_bounds__(TPB, 4)
void nep_p1(const float* __restrict__ W0, const float* __restrict__ W1,
            const float* __restrict__ g1, const float* __restrict__ b1,
            const int* __restrict__ norm,
            const float* __restrict__ p1, const short* __restrict__ gfnb,
            const short* __restrict__ gsidx, const char* __restrict__ gtt,
            float* __restrict__ p2, short* __restrict__ o2b)
{
    __shared__ __align__(16) short sW0[16 * 512];   // 16KB
    __shared__ __align__(16) short sW1[16 * 256];   // 8KB
    __shared__ float fred[8][64];                   // 2KB
    __shared__ float sAB1[64];
    __shared__ float rS[8][32], rQ[8][32];

    const int tid  = threadIdx.x;
    const int bid  = blockIdx.x;
    const int l    = tid & 63;
    const int wave = tid >> 6;
    const int p    = l & 15;
    const int hi   = l >> 4;
    const int base = bid * CHUNK;

    // stage W0/W1 (fp32 -> bf16)
    {
        const float4* W04 = (const float4*)W0;
        #pragma unroll
        for (int i = 0; i < 4; i++) {
            float4 v = W04[tid + i * TPB];
            short4 s;
            s.x = f2bf(v.x); s.y = f2bf(v.y); s.z = f2bf(v.z); s.w = f2bf(v.w);
            *(short4*)(sW0 + (tid + i * TPB) * 4) = s;
        }
        const float4* W14 = (const float4*)W1;
        #pragma unroll
        for (int i = 0; i < 2; i++) {
            float4 v = W14[tid + i * TPB];
            short4 s;
            s.x = f2bf(v.x); s.y = f2bf(v.y); s.z = f2bf(v.z); s.w = f2bf(v.w);
            *(short4*)(sW1 + (tid + i * TPB) * 4) = s;
        }
    }

    // redundant BN1 fold: deterministic, identical in every block
    {
        const int cc = tid & 63, j = tid >> 6;
        float s = 0.f;
        for (int blk = j; blk < NBLK; blk += 8) s += p1[blk * 64 + cc];
        fred[j][cc] = s;
    }
    __syncthreads();
    if (tid < 64) {
        float st = 0.f;
        #pragma unroll
        for (int jj = 0; jj < 8; jj++) st += fred[jj][tid];
        fred[0][tid] = st;
    }
    __syncthreads();
    if (tid < 32) {
        const float invE = 1.0f / (float)E_TOTAL;
        float mean = fred[0][tid] * invE;
        float var  = fred[0][32 + tid] * invE - mean * mean;
        float inv  = rsqrtf(var + 1e-5f);
        float a, b;
        if (*norm) { a = g1[tid] * inv; b = b1[tid] - mean * a; }
        else       { a = 1.f; b = 0.f; }
        sAB1[tid]      = a;
        sAB1[32 + tid] = b;
    }
    __syncthreads();

    float a1r[4], b1r[4], a1R[4], b1R[4];
    #pragma unroll
    for (int r = 0; r < 4; r++) {
        a1r[r] = sAB1[hi * 4 + r];      b1r[r] = sAB1[32 + hi * 4 + r];
        a1R[r] = sAB1[16 + hi * 4 + r]; b1R[r] = sAB1[48 + hi * 4 + r];
    }

    float s1[8], s2[8];
    #pragma unroll
    for (int c = 0; c < 8; c++) { s1[c] = 0.f; s2[c] = 0.f; }

    #pragma unroll 1
    for (int it = 0; it < 6; it++) {
        const int ti = wave + it * 8;
        if (ti >= MAXT) break;
        const int t = (int)gtt[bid * MAXT + ti];
        if (t < 0) break;                         // tiles are contiguous
        const int sp = (int)gsidx[bid * MAXT * 16 + ti * 16 + p];

        short8 bF = {0,0,0,0,0,0,0,0};
        if (hi < 2 && sp >= 0)
            bF = *(const short8*)(gfnb + (size_t)(base + sp) * 16 + hi * 8);
        short8 a0 = {0,0,0,0,0,0,0,0};
        short8 a1 = {0,0,0,0,0,0,0,0};
        if (hi < 2) {
            a0 = *(const short8*)(sW0 + t * 512 + p * 16 + hi * 8);
            a1 = *(const short8*)(sW0 + t * 512 + 256 + p * 16 + hi * 8);
        }
        f32x4 z = {0.f, 0.f, 0.f, 0.f};
        f32x4 c0 = __builtin_amdgcn_mfma_f32_16x16x32_bf16(a0, bF, z, 0, 0, 0);
        f32x4 c1 = __builtin_amdgcn_mfma_f32_16x16x32_bf16(a1, bF, z, 0, 0, 0);
        // c0[r] = out1[hi*4+r][p], c1[r] = out1[16+hi*4+r][p]

        const bool vs = (sp >= 0);
        short8 bS;
        #pragma unroll
        for (int r = 0; r < 4; r++) {
            float x0 = a1r[r] * c0[r] + b1r[r];
            float x1 = a1R[r] * c1[r] + b1R[r];
            bS[r]     = f2bf(vs ? silu_f(x0) : 0.f);
            bS[4 + r] = f2bf(vs ? silu_f(x1) : 0.f);
        }
        short8 a2v = {0,0,0,0,0,0,0,0};
        if (p < 8) {
            short4 A = *(const short4*)(sW1 + t * 256 + p * 32 + hi * 4);
            short4 B = *(const short4*)(sW1 + t * 256 + p * 32 + 16 + hi * 4);
            a2v[0] = A.x; a2v[1] = A.y; a2v[2] = A.z; a2v[3] = A.w;
            a2v[4] = B.x; a2v[5] = B.y; a2v[6] = B.z; a2v[7] = B.w;
        }
        f32x4 c2 = __builtin_amdgcn_mfma_f32_16x16x32_bf16(a2v, bS, z, 0, 0, 0);
        if (hi < 2 && sp >= 0) {
            short4 s;
            s.x = f2bf(c2[0]); s.y = f2bf(c2[1]); s.z = f2bf(c2[2]); s.w = f2bf(c2[3]);
            *(short4*)(o2b + (size_t)(base + sp) * 8 + hi * 4) = s;
        }
        #pragma unroll
        for (int r = 0; r < 4; r++) { s1[r] += c2[r]; s2[r] += c2[r] * c2[r]; }
    }

    #pragma unroll
    for (int c = 0; c < 4; c++) {
        float v1 = s1[c], v2 = s2[c];
        v1 += __shfl_xor(v1, 1, 64); v2 += __shfl_xor(v2, 1, 64);
        v1 += __shfl_xor(v1, 2, 64); v2 += __shfl_xor(v2, 2, 64);
        v1 += __shfl_xor(v1, 4, 64); v2 += __shfl_xor(v2, 4, 64);
        v1 += __shfl_xor(v1, 8, 64); v2 += __shfl_xor(v2, 8, 64);
        s1[c] = v1; s2[c] = v2;
    }
    if (p == 0 && hi < 2) {
        #pragma unroll
        for (int r = 0; r < 4; r++) {
            rS[wave][hi * 4 + r] = s1[r];
            rQ[wave][hi * 4 + r] = s2[r];
        }
    }
    __syncthreads();
    if (tid < 8) {
        float a = 0.f, b = 0.f;
        #pragma unroll
        for (int w = 0; w < 8; w++) { a += rS[w][tid]; b += rQ[w][tid]; }
        p2[bid * 16 + tid]     = a;
        p2[bid * 16 + 8 + tid] = b;
    }
}

// ---- fused BN2 finalize + streaming epilogue ----
__global__ __launch_bounds__(256)
void nep_bn2f(const short* __restrict__ o2b, const float* __restrict__ p2,
              const float* __restrict__ gamma, const float* __restrict__ beta,
              const int* __restrict__ norm, float* __restrict__ out)
{
    __shared__ float ssum[16][16];
    __shared__ float sA[8], sB[8];
    const int tid = threadIdx.x;
    {
        const int cc = tid & 15;
        const int j  = tid >> 4;
        float s = 0.f;
        for (int blk = j; blk < NBLK; blk += 16) s += p2[blk * 16 + cc];
        ssum[j][cc] = s;
    }
    __syncthreads();
    if (tid < 16) {
        float t = 0.f;
        #pragma unroll
        for (int jj = 0; jj < 16; jj++) t += ssum[jj][tid];
        ssum[0][tid] = t;
    }
    __syncthreads();
    if (tid < 8) {
        const float invE = 1.0f / (float)E_TOTAL;
        float mean = ssum[0][tid] * invE;
        float var  = ssum[0][8 + tid] * invE - mean * mean;
        float inv  = rsqrtf(var + 1e-5f);
        float a, b;
        if (*norm) { a = gamma[tid] * inv; b = beta[tid] - mean * a; }
        else       { a = 1.f; b = 0.f; }
        sA[tid] = a; sB[tid] = b;
    }
    __syncthreads();
    float a0 = sA[0], a1 = sA[1], a2 = sA[2], a3 = sA[3];
    float a4 = sA[4], a5 = sA[5], a6 = sA[6], a7 = sA[7];
    float b0 = sB[0], b1 = sB[1], b2 = sB[2], b3 = sB[3];
    float b4 = sB[4], b5 = sB[5], b6 = sB[6], b7 = sB[7];
    #pragma unroll
    for (int r = 0; r < 2; r++) {
        const int e = blockIdx.x * 256 + tid + r * (NBLK * 256);
        short8 v = *(const short8*)(o2b + (size_t)e * 8);
        float4 o0, o1;
        o0.x = silu_f(a0 * bf2f(v[0]) + b0);
        o0.y = silu_f(a1 * bf2f(v[1]) + b1);
        o0.z = silu_f(a2 * bf2f(v[2]) + b2);
        o0.w = silu_f(a3 * bf2f(v[3]) + b3);
        o1.x = silu_f(a4 * bf2f(v[4]) + b4);
        o1.y = silu_f(a5 * bf2f(v[5]) + b5);
        o1.z = silu_f(a6 * bf2f(v[6]) + b6);
        o1.w = silu_f(a7 * bf2f(v[7]) + b7);
        *(float4*)(out + (size_t)e * 8)     = o0;
        *(float4*)(out + (size_t)e * 8 + 4) = o1;
    }
}

extern "C" void kernel_launch(void* const* d_in, const int* in_sizes, int n_in,
                              void* d_out, int out_size, void* d_ws, size_t ws_size,
                              hipStream_t stream)
{
    const int*   ij   = (const int*)d_in[0];
    const float* fn   = (const float*)d_in[1];
    const float* W0   = (const float*)d_in[2];
    const float* W1   = (const float*)d_in[3];
    const float* g1   = (const float*)d_in[4];
    const float* b1   = (const float*)d_in[5];
    const float* g2   = (const float*)d_in[6];
    const float* b2   = (const float*)d_in[7];
    const int*   norm = (const int*)d_in[8];
    float* out = (float*)d_out;

    float* p1    = (float*)d_ws;                       // 512*64 f
    float* p2    = p1 + NBLK * 64;                     // 512*16 f
    short* gfnb  = (short*)(p2 + NBLK * 16);           // E*16 bf16 (8 MB)
    short* o2b   = gfnb + (size_t)E_TOTAL * 16;        // E*8 bf16 (4 MB)
    short* gsidx = o2b + (size_t)E_TOTAL * 8;          // 512*768 shorts (768 KB)
    char*  gtt   = (char*)(gsidx + NBLK * MAXT * 16);  // 512*48 chars

    nep_p0<<<NBLK, TPB, 0, stream>>>(ij, fn, W0, p1, gfnb, gsidx, gtt);
    nep_p1<<<NBLK, TPB, 0, stream>>>(W0, W1, g1, b1, norm, p1, gfnb, gsidx, gtt, p2, o2b);
    nep_bn2f<<<NBLK, 256, 0, stream>>>(o2b, p2, g2, b2, norm, out);
}

// Round 15
// 52.087 us; speedup vs baseline: 1.0773x; 1.0773x over previous
//
#include <hip/hip_runtime.h>

#define E_TOTAL 262144
#define TPB 512
#define NBLK 512
#define CHUNK 512
#define MAXG 32              // max 32-pair groups per chunk (hard bound 32)

typedef __attribute__((ext_vector_type(8))) short short8;
typedef __attribute__((ext_vector_type(16))) float f32x16;

__device__ __forceinline__ float silu_f(float x) { return x / (1.0f + __expf(-x)); }

// RNE float -> bf16 bits
__device__ __forceinline__ short f2bf(float f) {
    unsigned int u = __float_as_uint(f);
    u += 0x7fffu + ((u >> 16) & 1u);
    return (short)(u >> 16);
}
__device__ __forceinline__ float bf2f(short s) {
    return __uint_as_float(((unsigned int)(unsigned short)s) << 16);
}

// 32x32x16 engine. Per 32-pair group of one type:
//   C1[h=0..31][pair=0..31] = W0[t] @ fn   -- ONE mfma, K=16 exact (no padding).
// C layout (HW-verified m74/m101): col=lane&31, row=(reg&3)+8*(reg>>2)+4*(lane>>5).
// A/B fragged with OUR k-labeling k=(lane>>5)*8+reg on both sides (consistency
// argument, HW-validated for 16x16x32 in R9).
// PHASE 1: affine+SiLU on C1 regs; C1 regs 0..7 / 8..15 become B-frags of two
// accumulating 32x32x16 MFMAs against W1 pre-packed with the matching bijection.
template<int PHASE>
__global__ __launch_bounds__(TPB, 4)
void nep_main(const int* __restrict__ ij, const float* __restrict__ fn,
              const float* __restrict__ W0, const float* __restrict__ W1,
              const float* __restrict__ ab1g,
              float* __restrict__ partial, short* __restrict__ o2b)
{
    __shared__ __align__(16) short sW0[16 * 512];                     // 16KB [t][h][k]
    __shared__ __align__(16) short sW1p[(PHASE == 1) ? 4096 : 8];     // 8KB packed A2
    __shared__ __align__(16) short sfn[CHUNK * 16];                   // 16KB [pair][k]
    __shared__ int whist[8][16];
    __shared__ int woff[8][16];
    __shared__ int soff[16];
    __shared__ int tstart[17];
    __shared__ short slotp[MAXG * 32];   // group slot -> local pair (-1 pad)
    __shared__ char gtype[MAXG];
    __shared__ float rS[8][32], rQ[8][32];
    __shared__ float sAB1[64];

    const int tid  = threadIdx.x;
    const int bid  = blockIdx.x;
    const int l    = tid & 63;
    const int wave = tid >> 6;
    const int col  = l & 31;             // pair column within group / row for A
    const int gg   = l >> 5;             // k-slot group
    const int base = bid * CHUNK;

    const int t0 = ij[base + tid];
    const float4* f4g = (const float4*)(fn + (size_t)(base + tid) * 16);
    float4 u0 = f4g[0], u1 = f4g[1], u2 = f4g[2], u3 = f4g[3];

    // ---- ballot multi-split sort (stable: wave-major, lane-major) ----
    unsigned long long bl0 = __ballot(t0 & 1);
    unsigned long long bl1 = __ballot(t0 & 2);
    unsigned long long bl2 = __ballot(t0 & 4);
    unsigned long long bl3 = __ballot(t0 & 8);
    unsigned long long mself = ((t0 & 1) ? bl0 : ~bl0) & ((t0 & 2) ? bl1 : ~bl1)
                             & ((t0 & 4) ? bl2 : ~bl2) & ((t0 & 8) ? bl3 : ~bl3);
    const int rank_w = __popcll(mself & ((1ull << l) - 1ull));
    if (l < 16) {
        const int t = l;
        unsigned long long mt = ((t & 1) ? bl0 : ~bl0) & ((t & 2) ? bl1 : ~bl1)
                              & ((t & 4) ? bl2 : ~bl2) & ((t & 8) ? bl3 : ~bl3);
        whist[wave][t] = __popcll(mt);
    }
    ((int*)slotp)[tid] = -1;             // 512 ints == 1024 shorts of -1

    // ---- stage W0 (fp32 -> bf16, vectorized) ----
    {
        const float4* W04 = (const float4*)W0;
        #pragma unroll
        for (int i = 0; i < 4; i++) {
            float4 v = W04[tid + i * TPB];
            short4 s;
            s.x = f2bf(v.x); s.y = f2bf(v.y); s.z = f2bf(v.z); s.w = f2bf(v.w);
            *(short4*)(sW0 + (tid + i * TPB) * 4) = s;
        }
    }
    if constexpr (PHASE == 1) {
        // pre-pack W1 into A2-frag order: idx = t*256 + half*128 + n*16 + g*8 + r
        // value = W1[t][n][ch] with ch = (r&3) + 8*((r>>2)&1) + 4*g + 16*half
        #pragma unroll
        for (int i = 0; i < 8; i++) {
            int idx = tid + i * TPB;
            int t = idx >> 8, rem = idx & 255;
            int half = rem >> 7, n = (rem >> 4) & 7, g = (rem >> 3) & 1, r = rem & 7;
            int ch = (r & 3) + 8 * ((r >> 2) & 1) + 4 * g + 16 * half;
            sW1p[idx] = f2bf(W1[t * 256 + n * 32 + ch]);
        }
        if (tid < 64) sAB1[tid] = ab1g[tid];
    }
    // ---- stage fn (fp32 -> bf16): one pair per thread ----
    {
        short8 w0, w1;
        w0[0]=f2bf(u0.x); w0[1]=f2bf(u0.y); w0[2]=f2bf(u0.z); w0[3]=f2bf(u0.w);
        w0[4]=f2bf(u1.x); w0[5]=f2bf(u1.y); w0[6]=f2bf(u1.z); w0[7]=f2bf(u1.w);
        w1[0]=f2bf(u2.x); w1[1]=f2bf(u2.y); w1[2]=f2bf(u2.z); w1[3]=f2bf(u2.w);
        w1[4]=f2bf(u3.x); w1[5]=f2bf(u3.y); w1[6]=f2bf(u3.z); w1[7]=f2bf(u3.w);
        *(short8*)(sfn + tid * 16)     = w0;
        *(short8*)(sfn + tid * 16 + 8) = w1;
    }
    __syncthreads();

    if (tid < 16) {
        int acc = 0;
        #pragma unroll
        for (int w = 0; w < 8; w++) { woff[w][tid] = acc; acc += whist[w][tid]; }
        soff[tid] = acc;
    }
    __syncthreads();
    if (tid == 0) {
        int acc = 0;
        #pragma unroll
        for (int t = 0; t < 16; t++) { tstart[t] = acc; acc += (soff[t] + 31) >> 5; }
        tstart[16] = acc;
    }
    __syncthreads();
    {
        const int rank = woff[wave][t0] + rank_w;
        const int g = tstart[t0] + (rank >> 5);
        slotp[g * 32 + (rank & 31)] = (short)tid;
        gtype[g] = (char)t0;             // same-value race benign
    }
    __syncthreads();
    const int ngroups = tstart[16];      // <= 32

    float a1c[16], b1c[16];
    if constexpr (PHASE == 1) {
        #pragma unroll
        for (int c = 0; c < 16; c++) {
            int ch = (c & 3) + 8 * (c >> 2) + 4 * gg;
            a1c[c] = sAB1[ch];
            b1c[c] = sAB1[32 + ch];
        }
    }

    constexpr int NS = (PHASE == 0) ? 16 : 4;
    float s1[NS], s2[NS];
    #pragma unroll
    for (int c = 0; c < NS; c++) { s1[c] = 0.f; s2[c] = 0.f; }

    // ---- group loop: wave handles groups wave, wave+8, ... ----
    #pragma unroll 1
    for (int it = 0; it < 4; it++) {
        const int g = wave + it * 8;
        if (g >= ngroups) break;
        const int t  = (int)gtype[g];
        const int sp = (int)slotp[g * 32 + col];
        const bool vs = (sp >= 0);

        short8 bF = {0,0,0,0,0,0,0,0};
        if (vs) bF = *(const short8*)(sfn + sp * 16 + gg * 8);
        short8 aF = *(const short8*)(sW0 + t * 512 + col * 16 + gg * 8);
        f32x16 z = {0.f,0.f,0.f,0.f,0.f,0.f,0.f,0.f,0.f,0.f,0.f,0.f,0.f,0.f,0.f,0.f};
        f32x16 c1 = __builtin_amdgcn_mfma_f32_32x32x16_bf16(aF, bF, z, 0, 0, 0);
        // c1[r] = out1[(r&3)+8*(r>>2)+4*gg][col]

        if constexpr (PHASE == 0) {
            #pragma unroll
            for (int c = 0; c < 16; c++) { s1[c] += c1[c]; s2[c] += c1[c] * c1[c]; }
        } else {
            short8 b2a, b2b;
            #pragma unroll
            for (int r = 0; r < 8; r++) {
                float xa = a1c[r] * c1[r] + b1c[r];
                float xb = a1c[8 + r] * c1[8 + r] + b1c[8 + r];
                b2a[r] = f2bf(vs ? silu_f(xa) : 0.f);
                b2b[r] = f2bf(vs ? silu_f(xb) : 0.f);
            }
            short8 a2a = {0,0,0,0,0,0,0,0};
            short8 a2b = {0,0,0,0,0,0,0,0};
            if (col < 8) {
                a2a = *(const short8*)(sW1p + t * 256 + col * 16 + gg * 8);
                a2b = *(const short8*)(sW1p + t * 256 + 128 + col * 16 + gg * 8);
            }
            f32x16 c2 = __builtin_amdgcn_mfma_f32_32x32x16_bf16(a2a, b2a, z, 0, 0, 0);
            c2 = __builtin_amdgcn_mfma_f32_32x32x16_bf16(a2b, b2b, c2, 0, 0, 0);
            // c2[r] = out2[n=(r&3)+8*(r>>2)+4*gg][col]; valid n<8 -> regs 0..3
            if (vs) {
                short4 s;
                s.x = f2bf(c2[0]); s.y = f2bf(c2[1]); s.z = f2bf(c2[2]); s.w = f2bf(c2[3]);
                *(short4*)(o2b + (size_t)(base + sp) * 8 + 4 * gg) = s;
            }
            #pragma unroll
            for (int c = 0; c < 4; c++) { s1[c] += c2[c]; s2[c] += c2[c] * c2[c]; }
        }
    }

    // ---- reduce over pair columns (xor bits 0..4 stays within gg-group) ----
    #pragma unroll
    for (int c = 0; c < NS; c++) {
        float v1 = s1[c], v2 = s2[c];
        v1 += __shfl_xor(v1, 1, 64);  v2 += __shfl_xor(v2, 1, 64);
        v1 += __shfl_xor(v1, 2, 64);  v2 += __shfl_xor(v2, 2, 64);
        v1 += __shfl_xor(v1, 4, 64);  v2 += __shfl_xor(v2, 4, 64);
        v1 += __shfl_xor(v1, 8, 64);  v2 += __shfl_xor(v2, 8, 64);
        v1 += __shfl_xor(v1, 16, 64); v2 += __shfl_xor(v2, 16, 64);
        s1[c] = v1; s2[c] = v2;
    }
    if constexpr (PHASE == 0) {
        if (col == 0) {      // lanes 0 (gg=0) and 32 (gg=1): disjoint channels
            #pragma unroll
            for (int c = 0; c < 16; c++) {
                int ch = (c & 3) + 8 * (c >> 2) + 4 * gg;
                rS[wave][ch] = s1[c];
                rQ[wave][ch] = s2[c];
            }
        }
        __syncthreads();
        if (tid < 32) {
            float a = 0.f, b = 0.f;
            #pragma unroll
            for (int w = 0; w < 8; w++) { a += rS[w][tid]; b += rQ[w][tid]; }
            partial[bid * 64 + tid]      = a;
            partial[bid * 64 + 32 + tid] = b;
        }
    } else {
        if (col == 0) {
            #pragma unroll
            for (int c = 0; c < 4; c++) {
                rS[wave][4 * gg + c] = s1[c];
                rQ[wave][4 * gg + c] = s2[c];
            }
        }
        __syncthreads();
        if (tid < 8) {
            float a = 0.f, b = 0.f;
            #pragma unroll
            for (int w = 0; w < 8; w++) { a += rS[w][tid]; b += rQ[w][tid]; }
            partial[bid * 16 + tid]     = a;
            partial[bid * 16 + 8 + tid] = b;
        }
    }
}

// ---- fold BN1 stats into per-channel affine ----
template<int NS, int JW>
__global__ __launch_bounds__(1024)
void nep_finalize(const float* __restrict__ partial,
                  const float* __restrict__ gamma,
                  const float* __restrict__ beta,
                  const int* __restrict__ norm,
                  float* __restrict__ ab)
{
    __shared__ float ssum[JW][NS];
    __shared__ float ssq[JW][NS];
    const int c = threadIdx.x & (NS - 1);
    const int j = threadIdx.x / NS;
    float s = 0.f, q = 0.f;
    for (int blk = j; blk < NBLK; blk += JW) {
        s += partial[blk * (2 * NS) + c];
        q += partial[blk * (2 * NS) + NS + c];
    }
    ssum[j][c] = s; ssq[j][c] = q;
    __syncthreads();
    if (threadIdx.x < NS) {
        float st = 0.f, qt = 0.f;
        #pragma unroll
        for (int jj = 0; jj < JW; jj++) { st += ssum[jj][c]; qt += ssq[jj][c]; }
        const float invE = 1.0f / (float)E_TOTAL;
        float mean = st * invE;
        float var  = qt * invE - mean * mean;
        float inv  = rsqrtf(var + 1e-5f);
        float a, b;
        if (*norm) { a = gamma[c] * inv; b = beta[c] - mean * a; }
        else       { a = 1.f; b = 0.f; }
        ab[c] = a;
        ab[NS + c] = b;
    }
}

// ---- fused BN2 finalize + streaming epilogue ----
__global__ __launch_bounds__(256)
void nep_bn2f(const short* __restrict__ o2b, const float* __restrict__ p2,
              const float* __restrict__ gamma, const float* __restrict__ beta,
              const int* __restrict__ norm, float* __restrict__ out)
{
    __shared__ float ssum[16][16];
    __shared__ float sA[8], sB[8];
    const int tid = threadIdx.x;
    {
        const int cc = tid & 15;
        const int j  = tid >> 4;
        float s = 0.f;
        for (int blk = j; blk < NBLK; blk += 16) s += p2[blk * 16 + cc];
        ssum[j][cc] = s;
    }
    __syncthreads();
    if (tid < 16) {
        float t = 0.f;
        #pragma unroll
        for (int jj = 0; jj < 16; jj++) t += ssum[jj][tid];
        ssum[0][tid] = t;
    }
    __syncthreads();
    if (tid < 8) {
        const float invE = 1.0f / (float)E_TOTAL;
        float mean = ssum[0][tid] * invE;
        float var  = ssum[0][8 + tid] * invE - mean * mean;
        float inv  = rsqrtf(var + 1e-5f);
        float a, b;
        if (*norm) { a = gamma[tid] * inv; b = beta[tid] - mean * a; }
        else       { a = 1.f; b = 0.f; }
        sA[tid] = a; sB[tid] = b;
    }
    __syncthreads();
    float a0 = sA[0], a1 = sA[1], a2 = sA[2], a3 = sA[3];
    float a4 = sA[4], a5 = sA[5], a6 = sA[6], a7 = sA[7];
    float b0 = sB[0], b1 = sB[1], b2 = sB[2], b3 = sB[3];
    float b4 = sB[4], b5 = sB[5], b6 = sB[6], b7 = sB[7];
    #pragma unroll
    for (int r = 0; r < 2; r++) {
        const int e = blockIdx.x * 256 + tid + r * (NBLK * 256);
        short8 v = *(const short8*)(o2b + (size_t)e * 8);
        float4 o0, o1;
        o0.x = silu_f(a0 * bf2f(v[0]) + b0);
        o0.y = silu_f(a1 * bf2f(v[1]) + b1);
        o0.z = silu_f(a2 * bf2f(v[2]) + b2);
        o0.w = silu_f(a3 * bf2f(v[3]) + b3);
        o1.x = silu_f(a4 * bf2f(v[4]) + b4);
        o1.y = silu_f(a5 * bf2f(v[5]) + b5);
        o1.z = silu_f(a6 * bf2f(v[6]) + b6);
        o1.w = silu_f(a7 * bf2f(v[7]) + b7);
        *(float4*)(out + (size_t)e * 8)     = o0;
        *(float4*)(out + (size_t)e * 8 + 4) = o1;
    }
}

extern "C" void kernel_launch(void* const* d_in, const int* in_sizes, int n_in,
                              void* d_out, int out_size, void* d_ws, size_t ws_size,
                              hipStream_t stream)
{
    const int*   ij   = (const int*)d_in[0];
    const float* fn   = (const float*)d_in[1];
    const float* W0   = (const float*)d_in[2];
    const float* W1   = (const float*)d_in[3];
    const float* g1   = (const float*)d_in[4];
    const float* b1   = (const float*)d_in[5];
    const float* g2   = (const float*)d_in[6];
    const float* b2   = (const float*)d_in[7];
    const int*   norm = (const int*)d_in[8];
    float* out = (float*)d_out;

    float* p1  = (float*)d_ws;        // 512*64
    float* p2  = p1 + NBLK * 64;      // 512*16
    float* ab1 = p2 + NBLK * 16;      // 64
    short* o2b = (short*)(ab1 + 64);  // E*8 bf16 (4 MB)

    nep_main<0><<<NBLK, TPB, 0, stream>>>(ij, fn, W0, W1, nullptr, p1, nullptr);
    nep_finalize<32, 16><<<1, 512, 0, stream>>>(p1, g1, b1, norm, ab1);
    nep_main<1><<<NBLK, TPB, 0, stream>>>(ij, fn, W0, W1, ab1, p2, o2b);
    nep_bn2f<<<NBLK, 256, 0, stream>>>(o2b, p2, g2, b2, norm, out);
}